// Round 2
// baseline (103.711 us; speedup 1.0000x reference)
//
#include <hip/hip_runtime.h>
#include <hip/hip_bf16.h>

#define S 1024
#define C 384
#define NC 32
#define SHIFT 0.3f
#define NTILE 136
#define NBLK (NTILE * 4)

typedef __attribute__((ext_vector_type(4))) float f32x4;
typedef __attribute__((ext_vector_type(8))) short short8;

// f32 -> bf16 (round-to-nearest-even), raw-bit version (finite inputs only)
__device__ __forceinline__ unsigned int f2bf(float x) {
  unsigned int u = __builtin_bit_cast(unsigned int, x);
  unsigned int rb = ((u >> 16) & 1u) + 0x7fffu;
  return (u + rb) >> 16;
}
__device__ __forceinline__ unsigned int f2bf2(float lo, float hi) {
  return f2bf(lo) | (f2bf(hi) << 16);
}

// async global->LDS, 16B per lane; LDS dest is wave-uniform base + lane*16
__device__ __forceinline__ void gld16(void* lds, const void* g) {
  __builtin_amdgcn_global_load_lds(
      (const __attribute__((address_space(1))) void*)g,
      (__attribute__((address_space(3))) void*)lds, 16, 0, 0);
}

// ---- prep: normalize f -> bf16 fnb; exp(p)/p -> bf16 Eb/Pb; rowdot ----
__global__ __launch_bounds__(256) void k_prep(const float* __restrict__ f,
                                              const float* __restrict__ p,
                                              unsigned int* __restrict__ fnb,
                                              unsigned int* __restrict__ Eb,
                                              unsigned int* __restrict__ Pb,
                                              float* __restrict__ rowdot,
                                              float* __restrict__ accum) {
  // zero global accumulators (pos,neg,posc,negc,counter,pad) each replay
  if (blockIdx.x == 0 && threadIdx.x < 8) accum[threadIdx.x] = 0.f;

  if (blockIdx.x < 1024) {
    int lane = threadIdx.x & 63;
    int row = blockIdx.x * 4 + (threadIdx.x >> 6);
    const float* fr = f + (size_t)row * C;
    float2 v[3];
    float ss = 0.f;
#pragma unroll
    for (int j = 0; j < 3; ++j) {
      v[j] = *(const float2*)(fr + 2 * lane + 128 * j);
      ss = fmaf(v[j].x, v[j].x, fmaf(v[j].y, v[j].y, ss));
    }
#pragma unroll
    for (int m = 32; m >= 1; m >>= 1) ss += __shfl_xor(ss, m, 64);
    float s = 1.f / fmaxf(sqrtf(ss), 1e-12f);
    unsigned int* outr = fnb + (size_t)row * (C / 2);
#pragma unroll
    for (int j = 0; j < 3; ++j) outr[lane + 64 * j] = f2bf2(v[j].x * s, v[j].y * s);
  } else {
    int t = (blockIdx.x - 1024) * 256 + threadIdx.x;  // [0, 16384)
    int r = t >> 2, q = t & 3;
    const float* pr = p + (size_t)r * NC + q * 8;
    float4 a = *(const float4*)pr;
    float4 b = *(const float4*)(pr + 4);
    float ea0 = __expf(a.x), ea1 = __expf(a.y), ea2 = __expf(a.z), ea3 = __expf(a.w);
    float eb0 = __expf(b.x), eb1 = __expf(b.y), eb2 = __expf(b.z), eb3 = __expf(b.w);
    uint4 ue = make_uint4(f2bf2(ea0, ea1), f2bf2(ea2, ea3), f2bf2(eb0, eb1), f2bf2(eb2, eb3));
    uint4 up = make_uint4(f2bf2(a.x, a.y), f2bf2(a.z, a.w), f2bf2(b.x, b.y), f2bf2(b.z, b.w));
    *(uint4*)(Eb + r * 16 + q * 4) = ue;
    *(uint4*)(Pb + r * 16 + q * 4) = up;
    float s = ea0 * a.x + ea1 * a.y + ea2 * a.z + ea3 * a.w +
              eb0 * b.x + eb1 * b.y + eb2 * b.z + eb3 * b.w;
    s += __shfl_xor(s, 1, 64);
    s += __shfl_xor(s, 2, 64);
    if (q == 0) rowdot[r] = s;
  }
}

// ---- pairwise, TRIANGULAR tiling: 64x64 tiles, only tx>=ty (136 tiles/batch) ----
// 3-buffer LDS rotation, prefetch depth 2, ONE barrier per K-step:
//   [vmcnt(4)] [s_barrier] [stage tile kt+2 -> buf (kt+2)%3] [compute buf kt%3] [lgkm fence]
// Buffer-reuse safety: stage of buf b at iter kt+1 is after barrier kt+1; every wave's
// reads of buf b (iter kt) completed before that barrier (lgkmcnt(0) fence at end of kt).
// E/P epilogue fragments read straight from L2-hot global; final reduce fused via atomics.
__global__ __launch_bounds__(256, 2) void k_pair(
    const unsigned short* __restrict__ fnb, const unsigned short* __restrict__ Eb,
    const unsigned short* __restrict__ Pb, const float* __restrict__ rowdot,
    float* __restrict__ accum, float* __restrict__ out) {
  __shared__ unsigned short As[3][64 * 64];
  __shared__ unsigned short Bs[3][64 * 64];
  __shared__ float4 red[4];

  const int tid = threadIdx.x;
  const int lane = tid & 63;
  const int wave = tid >> 6;
  const int lan = lane & 15, quad = lane >> 4;
  const int n = blockIdx.y;

  // decode triangular tile index: bx -> (ty, tx) with tx >= ty
  int rem = blockIdx.x, ty = 0;
  while (rem >= 16 - ty) {
    rem -= 16 - ty;
    ++ty;
  }
  const int tx = ty + rem;
  const int sBase = ty * 64;
  const int lBase = tx * 64;

  // per-lane swizzled global source addresses for A/B staging (8 rows per gld16)
  const int r8 = lane >> 3, c8 = lane & 7;
  const char* gA = (const char*)fnb +
                   ((size_t)(n * S + sBase + 16 * wave + r8)) * 768 + ((c8 ^ r8) << 4);
  const char* gB = (const char*)fnb +
                   ((size_t)(n * S + lBase + 16 * wave + r8)) * 768 + ((c8 ^ r8) << 4);
  const int lOff = 16 * wave * 128;  // byte offset of this wave's 16-row LDS slice

#define STAGE(b, t)                                  \
  do {                                               \
    char* a_ = (char*)As[(b)] + lOff;                \
    char* b_ = (char*)Bs[(b)] + lOff;                \
    gld16(a_, gA + (t) * 128);                       \
    gld16(a_ + 8 * 128, gA + 8 * 768 + (t) * 128);   \
    gld16(b_, gB + (t) * 128);                       \
    gld16(b_ + 8 * 128, gB + 8 * 768 + (t) * 128);   \
  } while (0)

  // prologue: 2 tiles in flight
  STAGE(0, 0);
  STAGE(1, 1);

  f32x4 acc[4];
#pragma unroll
  for (int j = 0; j < 4; ++j) acc[j] = (f32x4){0.f, 0.f, 0.f, 0.f};

#pragma unroll
  for (int kt = 0; kt < 6; ++kt) {
    if (kt < 5)
      asm volatile("s_waitcnt vmcnt(4)" ::: "memory");  // oldest in-flight tile done
    else
      asm volatile("s_waitcnt vmcnt(0)" ::: "memory");
    __builtin_amdgcn_s_barrier();
    asm volatile("" ::: "memory");  // keep LDS reads below the barrier
    if (kt < 4) STAGE((kt + 2) % 3, kt + 2);
    const char* cA = (const char*)As[kt % 3];
    const char* cB = (const char*)Bs[kt % 3];
#pragma unroll
    for (int ks = 0; ks < 2; ++ks) {
      short8 af, bfr[4];
      {
        int rowA = 16 * wave + lan;
        af = *(const short8*)(cA + rowA * 128 + ((((ks << 2) | quad) ^ (lan & 7)) << 4));
      }
#pragma unroll
      for (int t = 0; t < 4; ++t) {
        int rowB = t * 16 + lan;
        bfr[t] = *(const short8*)(cB + rowB * 128 + ((((ks << 2) | quad) ^ (lan & 7)) << 4));
      }
#pragma unroll
      for (int j = 0; j < 4; ++j)
        acc[j] = __builtin_amdgcn_mfma_f32_16x16x32_bf16(af, bfr[j], acc[j], 0, 0, 0);
    }
    if (kt < 3)
      asm volatile("s_waitcnt lgkmcnt(0)" ::: "memory");  // reads done before next barrier
  }
#undef STAGE

  // epilogue: dual EP mini-GEMMs + weighted triangular reduction
  // C/D layout: row(m=s) = quad*4+reg, col(n=l) = lan
  // E/P fragments straight from global: each wave reads a contiguous 1KB (L2-hot).
  const size_t sRow = (size_t)(n * S + sBase + 16 * wave + lan) * 32 + quad * 8;
  short8 eas = *(const short8*)(Eb + sRow);
  short8 ps = *(const short8*)(Pb + sRow);
  float rd_s[4];
  {
    int gs0 = n * S + sBase + 16 * wave + quad * 4;
#pragma unroll
    for (int r = 0; r < 4; ++r) rd_s[r] = rowdot[gs0 + r];
  }

  float pos_s = 0.f, neg_s = 0.f, posc = 0.f, negc = 0.f;
#pragma unroll
  for (int j = 0; j < 4; ++j) {
    const size_t lRow = (size_t)(n * S + lBase + j * 16 + lan) * 32 + quad * 8;
    short8 pl = *(const short8*)(Pb + lRow);
    short8 eal = *(const short8*)(Eb + lRow);
    f32x4 z = (f32x4){0.f, 0.f, 0.f, 0.f};
    f32x4 ep1 = __builtin_amdgcn_mfma_f32_16x16x32_bf16(eas, pl, z, 0, 0, 0);
    f32x4 ep2 = __builtin_amdgcn_mfma_f32_16x16x32_bf16(ps, eal, z, 0, 0, 0);
    int gl = lBase + j * 16 + lan;
    float rd_l = rowdot[n * S + gl];
#pragma unroll
    for (int r = 0; r < 4; ++r) {
      int gs = sBase + 16 * wave + quad * 4 + r;
      float w1 = (gl >= gs) ? 1.f : 0.f;
      float w2 = (gl > gs) ? 1.f : 0.f;
      float fc = acc[j][r] - SHIFT;
      float contrib = w1 * (rd_s[r] - ep1[r]) + w2 * (rd_l - ep2[r]);
      float cnt = w1 + w2;
      if (fc > 0.f) {
        pos_s = fmaf(fc, contrib, pos_s);
        posc += cnt;
      } else if (fc < 0.f) {
        neg_s = fmaf(fc, contrib, neg_s);
        negc += cnt;
      }
    }
  }
#pragma unroll
  for (int m = 32; m >= 1; m >>= 1) {
    pos_s += __shfl_xor(pos_s, m, 64);
    neg_s += __shfl_xor(neg_s, m, 64);
    posc += __shfl_xor(posc, m, 64);
    negc += __shfl_xor(negc, m, 64);
  }
  if (lane == 0) red[wave] = make_float4(pos_s, neg_s, posc, negc);
  __syncthreads();
  if (tid == 0) {
    float4 t = red[0];
#pragma unroll
    for (int w = 1; w < 4; ++w) {
      t.x += red[w].x;
      t.y += red[w].y;
      t.z += red[w].z;
      t.w += red[w].w;
    }
    atomicAdd(&accum[0], t.x);
    atomicAdd(&accum[1], t.y);
    atomicAdd(&accum[2], t.z);
    atomicAdd(&accum[3], t.w);
    __threadfence();
    unsigned int old = atomicAdd((unsigned int*)(accum + 4), 1u);
    if (old == NBLK - 1) {
      __threadfence();
      // last block: coherent read of totals via atomic RMW (cross-XCD safe)
      float px = atomicAdd(&accum[0], 0.f);
      float ng = atomicAdd(&accum[1], 0.f);
      float pc = atomicAdd(&accum[2], 0.f);
      float nc = atomicAdd(&accum[3], 0.f);
      out[0] = px / pc;
      out[1] = ng / nc;
    }
  }
}

extern "C" void kernel_launch(void* const* d_in, const int* in_sizes, int n_in,
                              void* d_out, int out_size, void* d_ws, size_t ws_size,
                              hipStream_t stream) {
  const float* f = (const float*)d_in[0];  // feats [4,32,32,384] f32
  const float* p = (const float*)d_in[1];  // p_class [4,32,32,32] f32 (log-probs)
  float* out = (float*)d_out;              // [pos, neg]
  float* ws = (float*)d_ws;
  // ws layout (floats): rowdot @0 (4096) | accum @4096 (8) |
  // fnb @16384 (786432) | Eb @802816 (65536) | Pb @868352 (65536)
  float* rowdot = ws;
  float* accum = ws + 4096;
  unsigned int* fnb = (unsigned int*)(ws + 16384);
  unsigned int* Eb = (unsigned int*)(ws + 802816);
  unsigned int* Pb = (unsigned int*)(ws + 868352);

  k_prep<<<dim3(1088), dim3(256), 0, stream>>>(f, p, fnb, Eb, Pb, rowdot, accum);
  k_pair<<<dim3(NTILE, 4), dim3(256), 0, stream>>>((const unsigned short*)fnb,
                                                   (const unsigned short*)Eb,
                                                   (const unsigned short*)Pb, rowdot,
                                                   accum, out);
}